// Round 4
// baseline (6635.381 us; speedup 1.0000x reference)
//
#include <hip/hip_runtime.h>
#include <hip/hip_bf16.h>
#include <stdint.h>

// GatedGNN: B=256, N=80, D=1024, T=3
#define B_   256
#define N_   80
#define D_   1024
#define M_   (B_*N_)     // 20480 rows (b*80+node)
// Abuf row (bf16), SA_=8192: [a_hi(0:2048)|a_lo(2048:4096)|h_hi(4096:5120)|h_lo(5120:6144)|rh_hi(6144:7168)|rh_lo(7168:8192)]
#define SA_  8192
// W row (bf16), SW_=6144: [w_a_hi(0:2048)|w_a_lo(2048:4096)|w_u_hi(4096:5120)|w_u_lo(5120:6144)]
#define SW_  6144
#define KT_  144         // 144 BK=64 tiles -> K_eff = 9216 (3-term split product)

typedef __attribute__((ext_vector_type(8))) short bf16x8;   // 8 bf16 = 4 VGPRs
typedef __attribute__((ext_vector_type(4))) float f32x4;

__device__ __forceinline__ void async_cp16(const void* g, void* l) {
  __builtin_amdgcn_global_load_lds((const __attribute__((address_space(1))) unsigned int*)g,
                                   (__attribute__((address_space(3))) unsigned int*)l,
                                   16, 0, 0);
}
__device__ __forceinline__ float sigm_(float x) { return 1.0f / (1.0f + __expf(-x)); }
__device__ __forceinline__ float tanh_(float x) { return 2.0f / (1.0f + __expf(-2.0f * x)) - 1.0f; }
__device__ __forceinline__ void split_bf16(float v, __hip_bfloat16& hi, __hip_bfloat16& lo) {
  hi = __float2bfloat16(v);
  lo = __float2bfloat16(v - __bfloat162float(hi));
}

// ---------------- weight packing (hi/lo split): Wzr[2048][SW_], Wh[1024][SW_] ------------------
__global__ __launch_bounds__(256) void pack_weights(
    const float* __restrict__ W1w, const float* __restrict__ W1u,
    const float* __restrict__ W2w, const float* __restrict__ W2u,
    const float* __restrict__ W3w, const float* __restrict__ W3u,
    __hip_bfloat16* __restrict__ Wzr, __hip_bfloat16* __restrict__ Wh) {
  int idx = blockIdx.x * 256 + threadIdx.x;     // [0, 3072*3072)
  int n = idx / 3072, k = idx - n * 3072;       // n: 0..3071 output row, k: source col
  const float *Ww, *Wu; int nr; __hip_bfloat16* outrow;
  if (n < 1024)      { Ww = W1w; Wu = W1u; nr = n;        outrow = Wzr + (size_t)n * SW_; }
  else if (n < 2048) { Ww = W2w; Wu = W2u; nr = n - 1024; outrow = Wzr + (size_t)n * SW_; }
  else               { Ww = W3w; Wu = W3u; nr = n - 2048; outrow = Wh + (size_t)(n - 2048) * SW_; }
  float v; int chi, clo;
  if (k < 2048) { v = Ww[nr * 2048 + k];          chi = k;               clo = 2048 + k; }
  else          { v = Wu[nr * 1024 + (k - 2048)]; chi = 4096 + (k-2048); clo = 5120 + (k - 2048); }
  __hip_bfloat16 hi, lo; split_bf16(v, hi, lo);
  outrow[chi] = hi; outrow[clo] = lo;
}

// ---------------- propagation: a_in/a_out = inM/outM @ h[b] (fp32), split -> Abuf --------------
__global__ __launch_bounds__(256) void prop_kernel(
    const float* __restrict__ h, const float* __restrict__ inM,
    const float* __restrict__ outM, __hip_bfloat16* __restrict__ Abuf) {
  const int b = blockIdx.x;                        // chunk-local batch index
  const int d = blockIdx.y * 256 + threadIdx.x;
  const float* hb = h + (size_t)b * N_ * D_ + d;
  float hreg[N_];
  #pragma unroll
  for (int m = 0; m < N_; ++m) hreg[m] = hb[m * D_];
  __hip_bfloat16* Ab = Abuf + (size_t)b * N_ * SA_;
  #pragma unroll
  for (int m = 0; m < N_; ++m) {
    __hip_bfloat16 hi, lo; split_bf16(hreg[m], hi, lo);
    Ab[m * SA_ + 4096 + d] = hi; Ab[m * SA_ + 5120 + d] = lo;
  }
  for (int n = 0; n < N_; ++n) {
    float ai = 0.f, ao = 0.f;
    #pragma unroll
    for (int m = 0; m < N_; ++m) {
      ai += inM[n * N_ + m] * hreg[m];
      ao += outM[n * N_ + m] * hreg[m];
    }
    __hip_bfloat16 hi, lo;
    split_bf16(ai, hi, lo); Ab[n * SA_ + d] = hi;        Ab[n * SA_ + 2048 + d] = lo;
    split_bf16(ao, hi, lo); Ab[n * SA_ + 1024 + d] = hi; Ab[n * SA_ + 3072 + d] = lo;
  }
}

// ---------------- MFMA GEMM, 128x256 tile, BK=64, 3-term split-bf16 K plan --------------------
// wave-grid 2x2, wave-tile 64m x 128n, acc 4x8. AI = 85 FLOP/B (feed 39.5 B/cyc < L2 ~56).
// XCD-strip swizzle: xcd = flat&7 owns contiguous strip of m-tiles, n fastest.
template<bool IS_ZR>
__global__ __launch_bounds__(256, 2) void gemm_kernel(
    const __hip_bfloat16* __restrict__ Abuf,   // [rows][SA_] chunk-local
    const __hip_bfloat16* __restrict__ W,      // [Nout][SW_]
    const float* __restrict__ bw1, const float* __restrict__ bu1,
    const float* __restrict__ bw2, const float* __restrict__ bu2,
    const float* __restrict__ hcur,            // [rows][1024] fp32, chunk-local
    float* __restrict__ zbuf,                  // [rows][1024] fp32, chunk-local
    __hip_bfloat16* __restrict__ rhbase,       // = Abuf (rh at cols 6144/7168)
    float* __restrict__ hout,
    int mtiles) {
  __shared__ bf16x8 ldsA[1024];   // 16 KB: 128 m-rows x 4 k-chunks x 2 ks
  __shared__ bf16x8 ldsB[2048];   // 32 KB: 256 n-rows x 4 k-chunks x 2 ks

  const int ntiles = IS_ZR ? 8 : 4;            // 256-wide n tiles
  int mt, nt;
  if ((mtiles & 7) == 0) {
    const int flat = blockIdx.x;
    const int strip = mtiles >> 3;             // m-tiles per XCD
    const int xcd = flat & 7;
    const int loc = flat >> 3;                 // [0, strip*ntiles)
    mt = xcd * strip + loc / ntiles;
    nt = loc - (loc / ntiles) * ntiles;
  } else {
    mt = blockIdx.x / ntiles;
    nt = blockIdx.x - mt * ntiles;
  }
  const int m0 = mt * 128;
  const int n0 = nt * 256;

  const int tid  = threadIdx.x;
  const int lane = tid & 63;
  const int wave = tid >> 6;
  const int wm   = (wave & 1) * 64;
  const int wn   = (wave >> 1) * 128;
  const int l15  = lane & 15;
  const int l4   = lane >> 4;
  const int UBASE = IS_ZR ? 4096 : 6144;   // u-operand: h for ZR, r*h for H

  f32x4 acc[4][8];
  #pragma unroll
  for (int i = 0; i < 4; ++i)
    #pragma unroll
    for (int j = 0; j < 8; ++j) acc[i][j] = (f32x4){0.f, 0.f, 0.f, 0.f};

  const int aoff = (wm + l15) * 4 + l4;
  const int boff = (wn + l15) * 4 + l4;

  for (int kt = 0; kt < KT_; ++kt) {
    // segment plan: [0,32) a_hi*w_hi  [32,64) a_lo*w_hi  [64,96) a_hi*w_lo
    //               [96,112) u_hi*wu_hi [112,128) u_lo*wu_hi [128,144) u_hi*wu_lo
    int aoffk, woffk;
    if (kt < 64)       { aoffk = kt * 64;          woffk = (kt < 32) ? kt * 64 : kt * 64 - 2048; }
    else if (kt < 96)  { aoffk = kt * 64 - 4096;   woffk = kt * 64 - 2048; }
    else if (kt < 112) { int r = (kt - 96) * 64;  aoffk = UBASE + r;        woffk = 4096 + r; }
    else if (kt < 128) { int r = (kt - 112) * 64; aoffk = UBASE + 1024 + r; woffk = 4096 + r; }
    else               { int r = (kt - 128) * 64; aoffk = UBASE + r;        woffk = 5120 + r; }
    #pragma unroll
    for (int i = 0; i < 4; ++i) {              // A: 1024 chunks
      const int cidx = i * 256 + tid;
      const int q  = cidx & 3;
      const int mm = (cidx >> 2) & 127;
      const int ks = cidx >> 9;
      async_cp16(Abuf + (size_t)(m0 + mm) * SA_ + aoffk + ks * 32 + q * 8, &ldsA[cidx]);
    }
    #pragma unroll
    for (int j = 0; j < 8; ++j) {              // B: 2048 chunks
      const int cidx = j * 256 + tid;
      const int q  = cidx & 3;
      const int nn = (cidx >> 2) & 255;
      const int ks = cidx >> 10;
      async_cp16(W + (size_t)(n0 + nn) * SW_ + woffk + ks * 32 + q * 8, &ldsB[cidx]);
    }
    asm volatile("s_waitcnt vmcnt(0)" ::: "memory");
    __syncthreads();
    #pragma unroll
    for (int ks = 0; ks < 2; ++ks) {
      bf16x8 af[4], bb[8];
      #pragma unroll
      for (int mi = 0; mi < 4; ++mi) af[mi] = ldsA[ks * 512 + aoff + mi * 64];
      #pragma unroll
      for (int ni = 0; ni < 8; ++ni) bb[ni] = ldsB[ks * 1024 + boff + ni * 64];
      #pragma unroll
      for (int mi = 0; mi < 4; ++mi)
        #pragma unroll
        for (int ni = 0; ni < 8; ++ni)
          acc[mi][ni] = __builtin_amdgcn_mfma_f32_16x16x32_bf16(af[mi], bb[ni], acc[mi][ni], 0, 0, 0);
    }
    __syncthreads();
  }

  // epilogue: C/D layout col = lane&15, row = (lane>>4)*4 + reg
  #pragma unroll
  for (int mi = 0; mi < 4; ++mi) {
    #pragma unroll
    for (int p = 0; p < 4; ++p) {
      const int m = m0 + wm + mi * 16 + l4 * 4 + p;
      #pragma unroll
      for (int ni = 0; ni < 8; ++ni) {
        const int n = n0 + wn + ni * 16 + l15;
        float v = acc[mi][ni][p];
        if (IS_ZR) {
          if (n < 1024) {
            zbuf[(size_t)m * 1024 + n] = sigm_(v + bw1[n] + bu1[n]);
          } else {
            const int nn2 = n - 1024;
            float r = sigm_(v + bw2[nn2] + bu2[nn2]);
            float rh = r * hcur[(size_t)m * 1024 + nn2];
            __hip_bfloat16 hi, lo; split_bf16(rh, hi, lo);
            rhbase[(size_t)m * SA_ + 6144 + nn2] = hi;
            rhbase[(size_t)m * SA_ + 7168 + nn2] = lo;
          }
        } else {
          float hc = tanh_(v + bw1[n] + bu1[n]);
          float z  = zbuf[(size_t)m * 1024 + n];
          float ho = hcur[(size_t)m * 1024 + n];
          hout[(size_t)m * 1024 + n] = (1.0f - z) * ho + z * hc;
        }
      }
    }
  }
}

extern "C" void kernel_launch(void* const* d_in, const int* in_sizes, int n_in,
                              void* d_out, int out_size, void* d_ws, size_t ws_size,
                              hipStream_t stream) {
  const float* x    = (const float*)d_in[0];
  const float* inM  = (const float*)d_in[1];
  const float* outM = (const float*)d_in[2];
  const float* W1w  = (const float*)d_in[3];
  const float* b1w  = (const float*)d_in[4];
  const float* W1u  = (const float*)d_in[5];
  const float* b1u  = (const float*)d_in[6];
  const float* W2w  = (const float*)d_in[7];
  const float* b2w  = (const float*)d_in[8];
  const float* W2u  = (const float*)d_in[9];
  const float* b2u  = (const float*)d_in[10];
  const float* W3w  = (const float*)d_in[11];
  const float* b3w  = (const float*)d_in[12];
  const float* W3u  = (const float*)d_in[13];
  const float* b3u  = (const float*)d_in[14];
  float* hout = (float*)d_out;   // h lives in d_out across timesteps

  char* ws = (char*)d_ws;
  __hip_bfloat16* Wzr = (__hip_bfloat16*)ws;                 // 2048*6144*2 = 25,165,824 B
  __hip_bfloat16* Wh  = (__hip_bfloat16*)(ws + 25165824);    // 1024*6144*2 = 12,582,912 B
  const size_t fixed = 37748736;
  // per-batch-element chunk cost: Abuf 80*SA_*2 + zbuf 80*1024*4 = 1,638,400 B
  int Rb = 256;                                              // batch elems per chunk (mult of 8)
  while (Rb > 8 && fixed + (size_t)Rb * 1638400ull > ws_size) Rb -= 8;
  float* zbuf = (float*)(ws + fixed);                        // Rb*80*1024*4
  __hip_bfloat16* Abuf = (__hip_bfloat16*)(ws + fixed + (size_t)Rb * 327680ull);

  pack_weights<<<(3072 * 3072) / 256, 256, 0, stream>>>(
      W1w, W1u, W2w, W2u, W3w, W3u, Wzr, Wh);

  for (int t = 0; t < 3; ++t) {
    const float* hsrc = (t == 0) ? x : (const float*)hout;
    for (int b0 = 0; b0 < B_; b0 += Rb) {
      const int nb = (B_ - b0 < Rb) ? (B_ - b0) : Rb;
      const int rows = N_ * nb;                  // multiple of 640 -> /128 integral
      const int mtiles = rows / 128;
      const float* hc = hsrc + (size_t)b0 * N_ * D_;
      prop_kernel<<<dim3(nb, D_ / 256), 256, 0, stream>>>(hc, inM, outM, Abuf);
      gemm_kernel<true><<<mtiles * 8, 256, 0, stream>>>(
          Abuf, Wzr, b1w, b1u, b2w, b2u, hc, zbuf, Abuf, nullptr, mtiles);
      gemm_kernel<false><<<mtiles * 4, 256, 0, stream>>>(
          Abuf, Wh, b3w, b3u, nullptr, nullptr, hc, zbuf, nullptr,
          hout + (size_t)b0 * N_ * D_, mtiles);
    }
  }
}

// Round 5
// 5420.588 us; speedup vs baseline: 1.2241x; 1.2241x over previous
//
#include <hip/hip_runtime.h>
#include <hip/hip_bf16.h>
#include <stdint.h>

// GatedGNN: B=256, N=80, D=1024, T=3
#define B_   256
#define N_   80
#define D_   1024
#define M_   (B_*N_)     // 20480 rows (b*80+node)
// Abuf row (bf16), SA_=8192: [a_hi(0:2048)|a_lo(2048:4096)|h_hi(4096:5120)|h_lo(5120:6144)|rh_hi(6144:7168)|rh_lo(7168:8192)]
#define SA_  8192
// W row (bf16), SW_=6144: [w_a_hi(0:2048)|w_a_lo(2048:4096)|w_u_hi(4096:5120)|w_u_lo(5120:6144)]
#define SW_  6144
#define KT_  144         // 144 BK=64 tiles -> K_eff = 9216 (3-term split product)

typedef __attribute__((ext_vector_type(8))) short bf16x8;   // 8 bf16 = 4 VGPRs
typedef __attribute__((ext_vector_type(4))) float f32x4;

__device__ __forceinline__ void async_cp16(const void* g, void* l) {
  __builtin_amdgcn_global_load_lds((const __attribute__((address_space(1))) unsigned int*)g,
                                   (__attribute__((address_space(3))) unsigned int*)l,
                                   16, 0, 0);
}
__device__ __forceinline__ float sigm_(float x) { return 1.0f / (1.0f + __expf(-x)); }
__device__ __forceinline__ float tanh_(float x) { return 2.0f / (1.0f + __expf(-2.0f * x)) - 1.0f; }
__device__ __forceinline__ void split_bf16(float v, __hip_bfloat16& hi, __hip_bfloat16& lo) {
  hi = __float2bfloat16(v);
  lo = __float2bfloat16(v - __bfloat162float(hi));
}

// ---------------- weight packing (hi/lo split): Wzr[2048][SW_], Wh[1024][SW_] ------------------
__global__ __launch_bounds__(256) void pack_weights(
    const float* __restrict__ W1w, const float* __restrict__ W1u,
    const float* __restrict__ W2w, const float* __restrict__ W2u,
    const float* __restrict__ W3w, const float* __restrict__ W3u,
    __hip_bfloat16* __restrict__ Wzr, __hip_bfloat16* __restrict__ Wh) {
  int idx = blockIdx.x * 256 + threadIdx.x;     // [0, 3072*3072)
  int n = idx / 3072, k = idx - n * 3072;       // n: 0..3071 output row, k: source col
  const float *Ww, *Wu; int nr; __hip_bfloat16* outrow;
  if (n < 1024)      { Ww = W1w; Wu = W1u; nr = n;        outrow = Wzr + (size_t)n * SW_; }
  else if (n < 2048) { Ww = W2w; Wu = W2u; nr = n - 1024; outrow = Wzr + (size_t)n * SW_; }
  else               { Ww = W3w; Wu = W3u; nr = n - 2048; outrow = Wh + (size_t)(n - 2048) * SW_; }
  float v; int chi, clo;
  if (k < 2048) { v = Ww[nr * 2048 + k];          chi = k;               clo = 2048 + k; }
  else          { v = Wu[nr * 1024 + (k - 2048)]; chi = 4096 + (k-2048); clo = 5120 + (k - 2048); }
  __hip_bfloat16 hi, lo; split_bf16(v, hi, lo);
  outrow[chi] = hi; outrow[clo] = lo;
}

// ---------------- propagation: a_in/a_out = inM/outM @ h[b] (fp32), split -> Abuf --------------
__global__ __launch_bounds__(256) void prop_kernel(
    const float* __restrict__ h, const float* __restrict__ inM,
    const float* __restrict__ outM, __hip_bfloat16* __restrict__ Abuf) {
  const int b = blockIdx.x;                        // chunk-local batch index
  const int d = blockIdx.y * 256 + threadIdx.x;
  const float* hb = h + (size_t)b * N_ * D_ + d;
  float hreg[N_];
  #pragma unroll
  for (int m = 0; m < N_; ++m) hreg[m] = hb[m * D_];
  __hip_bfloat16* Ab = Abuf + (size_t)b * N_ * SA_;
  #pragma unroll
  for (int m = 0; m < N_; ++m) {
    __hip_bfloat16 hi, lo; split_bf16(hreg[m], hi, lo);
    Ab[m * SA_ + 4096 + d] = hi; Ab[m * SA_ + 5120 + d] = lo;
  }
  for (int n = 0; n < N_; ++n) {
    float ai = 0.f, ao = 0.f;
    #pragma unroll
    for (int m = 0; m < N_; ++m) {
      ai += inM[n * N_ + m] * hreg[m];
      ao += outM[n * N_ + m] * hreg[m];
    }
    __hip_bfloat16 hi, lo;
    split_bf16(ai, hi, lo); Ab[n * SA_ + d] = hi;        Ab[n * SA_ + 2048 + d] = lo;
    split_bf16(ao, hi, lo); Ab[n * SA_ + 1024 + d] = hi; Ab[n * SA_ + 3072 + d] = lo;
  }
}

// ---------------- MFMA GEMM, 160x128 tile, BK=64, 3-term split-bf16 K plan --------------------
// wave-grid 2x2, wave-tile 80m x 64n, acc 5x4 (80 AGPR). 36 KB LDS, 3 blocks/CU guaranteed.
// Balance: 160 MFMA/iter = 776 cyc vs 36 KB staged -> 47.5 B/cyc < per-CU L2 feed ceiling.
template<bool IS_ZR>
__global__ __launch_bounds__(256, 3) void gemm_kernel(
    const __hip_bfloat16* __restrict__ Abuf,   // [rows][SA_] chunk-local
    const __hip_bfloat16* __restrict__ W,      // [Nout][SW_]
    const float* __restrict__ bw1, const float* __restrict__ bu1,
    const float* __restrict__ bw2, const float* __restrict__ bu2,
    const float* __restrict__ hcur,            // [rows][1024] fp32, chunk-local
    float* __restrict__ zbuf,                  // [rows][1024] fp32, chunk-local
    __hip_bfloat16* __restrict__ rhbase,       // = Abuf (rh at cols 6144/7168)
    float* __restrict__ hout,
    int mtiles) {
  __shared__ bf16x8 ldsA[1280];   // 20 KB: ks(2) x 160 m-rows x 4 chunks
  __shared__ bf16x8 ldsB[1024];   // 16 KB: ks(2) x 128 n-rows x 4 chunks

  const int ntiles = IS_ZR ? 16 : 8;           // 128-wide n tiles
  int mt, nt;
  if ((mtiles & 7) == 0) {
    const int flat = blockIdx.x;
    const int strip = mtiles >> 3;             // m-tiles per XCD
    const int xcd = flat & 7;
    const int loc = flat >> 3;                 // [0, strip*ntiles)
    mt = xcd * strip + loc / ntiles;
    nt = loc - (loc / ntiles) * ntiles;
  } else {
    mt = blockIdx.x / ntiles;
    nt = blockIdx.x - mt * ntiles;
  }
  const int m0 = mt * 160;
  const int n0 = nt * 128;

  const int tid  = threadIdx.x;
  const int lane = tid & 63;
  const int wave = tid >> 6;
  const int wm   = (wave & 1) * 80;
  const int wn   = (wave >> 1) * 64;
  const int l15  = lane & 15;
  const int l4   = lane >> 4;
  const int UBASE = IS_ZR ? 4096 : 6144;   // u-operand: h for ZR, r*h for H

  f32x4 acc[5][4];
  #pragma unroll
  for (int i = 0; i < 5; ++i)
    #pragma unroll
    for (int j = 0; j < 4; ++j) acc[i][j] = (f32x4){0.f, 0.f, 0.f, 0.f};

  const int aoff = (wm + l15) * 4 + l4;
  const int boff = (wn + l15) * 4 + l4;

  for (int kt = 0; kt < KT_; ++kt) {
    // segment plan: [0,32) a_hi*w_hi  [32,64) a_lo*w_hi  [64,96) a_hi*w_lo
    //               [96,112) u_hi*wu_hi [112,128) u_lo*wu_hi [128,144) u_hi*wu_lo
    int aoffk, woffk;
    if (kt < 64)       { aoffk = kt * 64;          woffk = (kt < 32) ? kt * 64 : kt * 64 - 2048; }
    else if (kt < 96)  { aoffk = kt * 64 - 4096;   woffk = kt * 64 - 2048; }
    else if (kt < 112) { int r = (kt - 96) * 64;  aoffk = UBASE + r;        woffk = 4096 + r; }
    else if (kt < 128) { int r = (kt - 112) * 64; aoffk = UBASE + 1024 + r; woffk = 4096 + r; }
    else               { int r = (kt - 128) * 64; aoffk = UBASE + r;        woffk = 5120 + r; }
    #pragma unroll
    for (int i = 0; i < 5; ++i) {              // A: 1280 chunks, 5 per thread
      const int cidx = i * 256 + tid;
      const int ks = cidx / 640;
      const int rr = cidx - ks * 640;
      const int q  = rr & 3;
      const int mm = rr >> 2;
      async_cp16(Abuf + (size_t)(m0 + mm) * SA_ + aoffk + ks * 32 + q * 8, &ldsA[cidx]);
    }
    #pragma unroll
    for (int j = 0; j < 4; ++j) {              // B: 1024 chunks, 4 per thread
      const int cidx = j * 256 + tid;
      const int q  = cidx & 3;
      const int nn = (cidx >> 2) & 127;
      const int ks = cidx >> 9;
      async_cp16(W + (size_t)(n0 + nn) * SW_ + woffk + ks * 32 + q * 8, &ldsB[cidx]);
    }
    asm volatile("s_waitcnt vmcnt(0)" ::: "memory");
    __syncthreads();
    #pragma unroll
    for (int ks = 0; ks < 2; ++ks) {
      bf16x8 af[5], bb[4];
      #pragma unroll
      for (int mi = 0; mi < 5; ++mi) af[mi] = ldsA[ks * 640 + aoff + mi * 64];
      #pragma unroll
      for (int ni = 0; ni < 4; ++ni) bb[ni] = ldsB[ks * 512 + boff + ni * 64];
      #pragma unroll
      for (int mi = 0; mi < 5; ++mi)
        #pragma unroll
        for (int ni = 0; ni < 4; ++ni)
          acc[mi][ni] = __builtin_amdgcn_mfma_f32_16x16x32_bf16(af[mi], bb[ni], acc[mi][ni], 0, 0, 0);
    }
    __syncthreads();
  }

  // epilogue: C/D layout col = lane&15, row = (lane>>4)*4 + reg
  #pragma unroll
  for (int mi = 0; mi < 5; ++mi) {
    #pragma unroll
    for (int p = 0; p < 4; ++p) {
      const int m = m0 + wm + mi * 16 + l4 * 4 + p;
      #pragma unroll
      for (int ni = 0; ni < 4; ++ni) {
        const int n = n0 + wn + ni * 16 + l15;
        float v = acc[mi][ni][p];
        if (IS_ZR) {
          if (n < 1024) {
            zbuf[(size_t)m * 1024 + n] = sigm_(v + bw1[n] + bu1[n]);
          } else {
            const int nn2 = n - 1024;
            float r = sigm_(v + bw2[nn2] + bu2[nn2]);
            float rh = r * hcur[(size_t)m * 1024 + nn2];
            __hip_bfloat16 hi, lo; split_bf16(rh, hi, lo);
            rhbase[(size_t)m * SA_ + 6144 + nn2] = hi;
            rhbase[(size_t)m * SA_ + 7168 + nn2] = lo;
          }
        } else {
          float hc = tanh_(v + bw1[n] + bu1[n]);
          float z  = zbuf[(size_t)m * 1024 + n];
          float ho = hcur[(size_t)m * 1024 + n];
          hout[(size_t)m * 1024 + n] = (1.0f - z) * ho + z * hc;
        }
      }
    }
  }
}

extern "C" void kernel_launch(void* const* d_in, const int* in_sizes, int n_in,
                              void* d_out, int out_size, void* d_ws, size_t ws_size,
                              hipStream_t stream) {
  const float* x    = (const float*)d_in[0];
  const float* inM  = (const float*)d_in[1];
  const float* outM = (const float*)d_in[2];
  const float* W1w  = (const float*)d_in[3];
  const float* b1w  = (const float*)d_in[4];
  const float* W1u  = (const float*)d_in[5];
  const float* b1u  = (const float*)d_in[6];
  const float* W2w  = (const float*)d_in[7];
  const float* b2w  = (const float*)d_in[8];
  const float* W2u  = (const float*)d_in[9];
  const float* b2u  = (const float*)d_in[10];
  const float* W3w  = (const float*)d_in[11];
  const float* b3w  = (const float*)d_in[12];
  const float* W3u  = (const float*)d_in[13];
  const float* b3u  = (const float*)d_in[14];
  float* hout = (float*)d_out;   // h lives in d_out across timesteps

  char* ws = (char*)d_ws;
  __hip_bfloat16* Wzr = (__hip_bfloat16*)ws;                 // 2048*6144*2 = 25,165,824 B
  __hip_bfloat16* Wh  = (__hip_bfloat16*)(ws + 25165824);    // 1024*6144*2 = 12,582,912 B
  const size_t fixed = 37748736;
  // per-batch-element chunk cost: Abuf 80*SA_*2 + zbuf 80*1024*4 = 1,638,400 B
  int Rb = 256;                                              // batch elems per chunk (mult of 8)
  while (Rb > 8 && fixed + (size_t)Rb * 1638400ull > ws_size) Rb -= 8;
  float* zbuf = (float*)(ws + fixed);                        // Rb*80*1024*4
  __hip_bfloat16* Abuf = (__hip_bfloat16*)(ws + fixed + (size_t)Rb * 327680ull);

  pack_weights<<<(3072 * 3072) / 256, 256, 0, stream>>>(
      W1w, W1u, W2w, W2u, W3w, W3u, Wzr, Wh);

  for (int t = 0; t < 3; ++t) {
    const float* hsrc = (t == 0) ? x : (const float*)hout;
    for (int b0 = 0; b0 < B_; b0 += Rb) {
      const int nb = (B_ - b0 < Rb) ? (B_ - b0) : Rb;
      const int rows = N_ * nb;                  // 80*nb, nb mult of 8 -> /160 integral
      const int mtiles = rows / 160;
      const float* hc = hsrc + (size_t)b0 * N_ * D_;
      prop_kernel<<<dim3(nb, D_ / 256), 256, 0, stream>>>(hc, inM, outM, Abuf);
      gemm_kernel<true><<<mtiles * 16, 256, 0, stream>>>(
          Abuf, Wzr, b1w, b1u, b2w, b2u, hc, zbuf, Abuf, nullptr, mtiles);
      gemm_kernel<false><<<mtiles * 8, 256, 0, stream>>>(
          Abuf, Wh, b3w, b3u, nullptr, nullptr, hc, zbuf, nullptr,
          hout + (size_t)b0 * N_ * D_, mtiles);
    }
  }
}